// Round 1
// baseline (731.415 us; speedup 1.0000x reference)
//
#include <hip/hip_runtime.h>

#define IN_DIM 32
#define OUT_DIM 32

// Phase 1: Y = X @ W  (row-major X: n_nodes x 32, W: 32 x 32)
// One thread per row; W staged in LDS (all lanes read same W element per
// iteration -> LDS broadcast, conflict-free).
__global__ __launch_bounds__(256) void gemm_xw(const float* __restrict__ X,
                                               const float* __restrict__ W,
                                               float* __restrict__ Y,
                                               int n_nodes) {
    __shared__ float Wlds[IN_DIM * OUT_DIM];
    const int tid = threadIdx.x;
    for (int i = tid; i < IN_DIM * OUT_DIM; i += 256) Wlds[i] = W[i];
    __syncthreads();

    const int r = blockIdx.x * 256 + tid;
    if (r >= n_nodes) return;

    float x[IN_DIM];
    const float4* xr = (const float4*)(X + (size_t)r * IN_DIM);
#pragma unroll
    for (int i = 0; i < IN_DIM / 4; ++i) {
        float4 v = xr[i];
        x[4 * i + 0] = v.x; x[4 * i + 1] = v.y;
        x[4 * i + 2] = v.z; x[4 * i + 3] = v.w;
    }

    float acc[OUT_DIM];
#pragma unroll
    for (int c = 0; c < OUT_DIM; ++c) acc[c] = 0.0f;

#pragma unroll
    for (int k = 0; k < IN_DIM; ++k) {
        const float xk = x[k];
#pragma unroll
        for (int c = 0; c < OUT_DIM; ++c)
            acc[c] = fmaf(xk, Wlds[k * OUT_DIM + c], acc[c]);
    }

    float4* yr = (float4*)(Y + (size_t)r * OUT_DIM);
#pragma unroll
    for (int i = 0; i < OUT_DIM / 4; ++i)
        yr[i] = make_float4(acc[4 * i + 0], acc[4 * i + 1],
                            acc[4 * i + 2], acc[4 * i + 3]);
}

// Phase 2: out[dst[e]] += Y[src[e]]  via device-scope float atomics.
// 8 lanes per edge, each lane gathers a float4 and issues 4 atomicAdds.
// 32 edges per 256-thread block.
__global__ __launch_bounds__(256) void scatter_add(const float* __restrict__ Y,
                                                   const int* __restrict__ src,
                                                   const int* __restrict__ dst,
                                                   float* __restrict__ out,
                                                   int n_edges) {
    const int tid = threadIdx.x;
    const int e = blockIdx.x * 32 + (tid >> 3);
    if (e >= n_edges) return;
    const int c4 = tid & 7;

    const int s = src[e];
    const int d = dst[e];

    const float4 v = ((const float4*)Y)[(size_t)s * (IN_DIM / 4) + c4];
    float* o = out + (size_t)d * OUT_DIM + c4 * 4;
    atomicAdd(o + 0, v.x);
    atomicAdd(o + 1, v.y);
    atomicAdd(o + 2, v.z);
    atomicAdd(o + 3, v.w);
}

extern "C" void kernel_launch(void* const* d_in, const int* in_sizes, int n_in,
                              void* d_out, int out_size, void* d_ws, size_t ws_size,
                              hipStream_t stream) {
    const float* X   = (const float*)d_in[0];
    const float* W   = (const float*)d_in[1];
    const int*   src = (const int*)d_in[2];
    const int*   dst = (const int*)d_in[3];
    float* out = (float*)d_out;

    const int n_nodes = in_sizes[0] / IN_DIM;
    const int n_edges = in_sizes[2];

    float* Y = (float*)d_ws;  // n_nodes * OUT_DIM floats (12.8 MB)

    // d_out is poisoned to 0xAA before every call -> zero it (capture-legal).
    hipMemsetAsync(d_out, 0, (size_t)out_size * sizeof(float), stream);

    gemm_xw<<<(n_nodes + 255) / 256, 256, 0, stream>>>(X, W, Y, n_nodes);
    scatter_add<<<(n_edges + 31) / 32, 256, 0, stream>>>(Y, src, dst, out, n_edges);
}

// Round 2
// 319.415 us; speedup vs baseline: 2.2899x; 2.2899x over previous
//
#include <hip/hip_runtime.h>

#define N_DIM 32          // IN_DIM == OUT_DIM == 32
#define SCAN_BLK 256      // threads for partial-sum blocks

// ---------------- Phase A: CSR build (counting sort by dst) ----------------

// A1: histogram of dst
__global__ __launch_bounds__(256) void k_hist(const int* __restrict__ dst,
                                              int* __restrict__ counts,
                                              int n_edges) {
    int e = blockIdx.x * 256 + threadIdx.x;
    if (e < n_edges) atomicAdd(&counts[dst[e]], 1);
}

// A2a: per-block partial sums of counts
__global__ __launch_bounds__(SCAN_BLK) void k_blocksum(const int* __restrict__ counts,
                                                       int* __restrict__ blocksum,
                                                       int n) {
    __shared__ int sc[SCAN_BLK];
    int gid = blockIdx.x * SCAN_BLK + threadIdx.x;
    sc[threadIdx.x] = (gid < n) ? counts[gid] : 0;
    __syncthreads();
    for (int off = SCAN_BLK / 2; off > 0; off >>= 1) {
        if (threadIdx.x < off) sc[threadIdx.x] += sc[threadIdx.x + off];
        __syncthreads();
    }
    if (threadIdx.x == 0) blocksum[blockIdx.x] = sc[0];
}

// A2b: exclusive scan of blocksums (one block, 512 threads; nb <= 512)
__global__ __launch_bounds__(512) void k_scan_blocks(const int* __restrict__ blocksum,
                                                     int* __restrict__ blockoff,
                                                     int nb) {
    __shared__ int sc[512];
    int t = threadIdx.x;
    int v = (t < nb) ? blocksum[t] : 0;
    sc[t] = v;
    __syncthreads();
    for (int off = 1; off < 512; off <<= 1) {
        int x = (t >= off) ? sc[t - off] : 0;
        __syncthreads();
        sc[t] += x;
        __syncthreads();
    }
    if (t < nb) blockoff[t] = sc[t] - v;   // exclusive
}

// A2c: local exclusive scan + block offset -> offsets[], cursor[] copy
__global__ __launch_bounds__(SCAN_BLK) void k_scan_final(const int* __restrict__ counts,
                                                         const int* __restrict__ blockoff,
                                                         int* __restrict__ offsets,
                                                         int* __restrict__ cursor,
                                                         int n) {
    __shared__ int sc[SCAN_BLK];
    int t = threadIdx.x;
    int gid = blockIdx.x * SCAN_BLK + t;
    int v = (gid < n) ? counts[gid] : 0;
    sc[t] = v;
    __syncthreads();
    for (int off = 1; off < SCAN_BLK; off <<= 1) {
        int x = (t >= off) ? sc[t - off] : 0;
        __syncthreads();
        sc[t] += x;
        __syncthreads();
    }
    if (gid < n) {
        int excl = blockoff[blockIdx.x] + sc[t] - v;
        offsets[gid] = excl;
        cursor[gid] = excl;
        if (gid == n - 1) offsets[n] = excl + v;   // total
    }
}

// A3: bin edges — sorted_src[pos] = src, pos allocated via cursor atomics
__global__ __launch_bounds__(256) void k_bin(const int* __restrict__ src,
                                             const int* __restrict__ dst,
                                             int* __restrict__ cursor,
                                             int* __restrict__ sorted_src,
                                             int n_edges) {
    int e = blockIdx.x * 256 + threadIdx.x;
    if (e < n_edges) {
        int pos = atomicAdd(&cursor[dst[e]], 1);
        sorted_src[pos] = src[e];
    }
}

// ---------------- Phase B: fused aggregate + matvec ----------------
// 8 lanes per node (lane j owns columns 4j..4j+3); 32 nodes per 256-thr block.
// agg row -> LDS (padded stride 33 to kill 8-way bank conflicts) -> matvec W.
__global__ __launch_bounds__(256) void k_agg_gemm(const float* __restrict__ X,
                                                  const float* __restrict__ W,
                                                  const int* __restrict__ offsets,
                                                  const int* __restrict__ sorted_src,
                                                  float* __restrict__ out,
                                                  int n_nodes) {
    __shared__ float Wlds[N_DIM * N_DIM];
    __shared__ float aggL[32][N_DIM + 1];

    const int tid = threadIdx.x;
    for (int i = tid; i < N_DIM * N_DIM; i += 256) Wlds[i] = W[i];

    const int ln = tid >> 3;              // local node 0..31
    const int j = tid & 7;                // column-quad 0..7
    const int node = blockIdx.x * 32 + ln;

    float4 acc = make_float4(0.f, 0.f, 0.f, 0.f);
    if (node < n_nodes) {
        const int s0 = offsets[node];
        const int s1 = offsets[node + 1];
        for (int e = s0; e < s1; ++e) {
            const int s = sorted_src[e];
            const float4 v = ((const float4*)X)[(size_t)s * (N_DIM / 4) + j];
            acc.x += v.x; acc.y += v.y; acc.z += v.z; acc.w += v.w;
        }
    }
    aggL[ln][4 * j + 0] = acc.x;
    aggL[ln][4 * j + 1] = acc.y;
    aggL[ln][4 * j + 2] = acc.z;
    aggL[ln][4 * j + 3] = acc.w;
    __syncthreads();

    if (node < n_nodes) {
        float o0 = 0.f, o1 = 0.f, o2 = 0.f, o3 = 0.f;
#pragma unroll
        for (int k = 0; k < N_DIM; ++k) {
            const float a = aggL[ln][k];
            o0 = fmaf(a, Wlds[k * N_DIM + 4 * j + 0], o0);
            o1 = fmaf(a, Wlds[k * N_DIM + 4 * j + 1], o1);
            o2 = fmaf(a, Wlds[k * N_DIM + 4 * j + 2], o2);
            o3 = fmaf(a, Wlds[k * N_DIM + 4 * j + 3], o3);
        }
        ((float4*)out)[(size_t)node * (N_DIM / 4) + j] = make_float4(o0, o1, o2, o3);
    }
}

extern "C" void kernel_launch(void* const* d_in, const int* in_sizes, int n_in,
                              void* d_out, int out_size, void* d_ws, size_t ws_size,
                              hipStream_t stream) {
    const float* X   = (const float*)d_in[0];
    const float* W   = (const float*)d_in[1];
    const int*   src = (const int*)d_in[2];
    const int*   dst = (const int*)d_in[3];
    float* out = (float*)d_out;

    const int n_nodes = in_sizes[0] / N_DIM;
    const int n_edges = in_sizes[2];

    const int nb = (n_nodes + SCAN_BLK - 1) / SCAN_BLK;   // scan blocks (<=512)

    // workspace layout (ints)
    int* counts     = (int*)d_ws;                 // n_nodes
    int* offsets    = counts + n_nodes;           // n_nodes + 1
    int* cursor     = offsets + n_nodes + 1;      // n_nodes
    int* blocksum   = cursor + n_nodes;           // nb (<=512)
    int* blockoff   = blocksum + 512;             // nb
    int* sorted_src = blockoff + 512;             // n_edges

    // zero the histogram (d_ws is re-poisoned to 0xAA every call)
    hipMemsetAsync(counts, 0, (size_t)n_nodes * sizeof(int), stream);

    k_hist<<<(n_edges + 255) / 256, 256, 0, stream>>>(dst, counts, n_edges);
    k_blocksum<<<nb, SCAN_BLK, 0, stream>>>(counts, blocksum, n_nodes);
    k_scan_blocks<<<1, 512, 0, stream>>>(blocksum, blockoff, nb);
    k_scan_final<<<nb, SCAN_BLK, 0, stream>>>(counts, blockoff, offsets, cursor, n_nodes);
    k_bin<<<(n_edges + 255) / 256, 256, 0, stream>>>(src, dst, cursor, sorted_src, n_edges);
    k_agg_gemm<<<(n_nodes + 31) / 32, 256, 0, stream>>>(X, W, offsets, sorted_src, out, n_nodes);
}